// Round 13
// baseline (112.970 us; speedup 1.0000x reference)
//
#include <hip/hip_runtime.h>
#include <math.h>

// Problem constants
#define T_LEN   500
#define C_CH    128
#define DM      128     // D_MODEL
#define N_OCC   21
#define KSZ     9
#define N_OUT   40
#define LOG2E   1.44269504088896340736f

typedef _Float16 f16x8 __attribute__((ext_vector_type(8)));
typedef _Float16 f16x2 __attribute__((ext_vector_type(2)));
typedef float    f32x16 __attribute__((ext_vector_type(16)));

union pair_u { unsigned int u; f16x2 h; };

__device__ __forceinline__ float exp2_fast(float y) {
#if __has_builtin(__builtin_amdgcn_exp2f)
    return __builtin_amdgcn_exp2f(y);
#else
    return exp2f(y);
#endif
}

// y = x * log2(e)  ->  returns selu(x).
__device__ __forceinline__ float selu2(float y) {
    const float c1 = 0.7282904300f;          // lambda * ln2
    const float la = 1.7580993408473766f;    // lambda * alpha
    float e = exp2_fast(y);
    return y > 0.f ? c1 * y : fmaf(la, e, -la);
}

__device__ __forceinline__ f32x16 zero16() {
    f32x16 z;
#pragma unroll
    for (int j = 0; j < 16; ++j) z[j] = 0.f;
    return z;
}

// ---------------------------------------------------------------------------
// Combined prep:
//  (1) wqT[(l*21+o)*9+k][D] = wq[l,D,o,k] * log2e
//  (2) wkh/wvh in MFMA A-fragment layout, f16, * log2e
//  (3) zero the head completion counter (graph-replay determinism)
// ---------------------------------------------------------------------------
__global__ void prep_kernel(const float* __restrict__ wq,
                            const float* __restrict__ wk, const float* __restrict__ wv,
                            float* __restrict__ wqT,
                            _Float16* __restrict__ wkh, _Float16* __restrict__ wvh,
                            unsigned int* __restrict__ head_cnt)
{
    int idx = blockIdx.x * 256 + threadIdx.x;          // 65536 threads
    if (idx == 0) *head_cnt = 0;
    if (idx < 2 * N_OCC * KSZ * DM) {
        int D  = idx & 127;
        int r  = idx >> 7;
        int k  = r % KSZ;
        int r2 = r / KSZ;
        int o  = r2 % N_OCC;
        int l  = r2 / N_OCC;
        wqT[idx] = wq[(((size_t)l * DM + D) * N_OCC + o) * KSZ + k] * LOG2E;
    }
    if (idx < 2 * C_CH * 4 * 64) {
        int lane = idx & 63;
        int ch   = (idx >> 6) & 3;
        int c    = (idx >> 8) & 127;
        int l    = idx >> 15;
        int tcol = lane & 31, hi = lane >> 5;
        int D    = ch * 32 + tcol;
        const float* wkp = wk + ((size_t)l * C_CH * DM + (size_t)c * DM + D) * KSZ;
        const float* wvp = wv + ((size_t)l * C_CH * DM + (size_t)c * DM + D) * KSZ;
#pragma unroll
        for (int j = 0; j < 8; ++j) {
            int k = 8 * hi + j;
            wkh[(size_t)idx * 8 + j] = (k < KSZ) ? (_Float16)(wkp[k] * LOG2E) : (_Float16)0.f;
            wvh[(size_t)idx * 8 + j] = (k < KSZ) ? (_Float16)(wvp[k] * LOG2E) : (_Float16)0.f;
        }
    }
}

// ---------------------------------------------------------------------------
// Q conv, writing Qpack[b][tile][ch][g][t32][i2] (float4-friendly):
//   D = ch*32 + 8I + 4hi + i2, g = 2I+hi
// grid (125, 8), block 128 (one thread per D), 4 t per block
// ---------------------------------------------------------------------------
#define ATCH 4
__global__ __launch_bounds__(128) void qconv_kernel(
    const float* __restrict__ xin, const int* __restrict__ occ,
    const float* __restrict__ wqT, float* __restrict__ qtP, int l)
{
    const int b  = blockIdx.y;
    const int t0 = blockIdx.x * ATCH;
    const int D  = threadIdx.x;
    __shared__ float xo[N_OCC][ATCH + 8];
    for (int i = threadIdx.x; i < N_OCC * (ATCH + 8); i += 128) {
        int o = i / (ATCH + 8), j = i % (ATCH + 8);
        int tg = t0 + j - 4;
        xo[o][j] = (tg >= 0 && tg < T_LEN)
                     ? xin[((size_t)b * C_CH + occ[o]) * T_LEN + tg] : 0.f;
    }
    __syncthreads();

    float acc[ATCH];
#pragma unroll
    for (int tt = 0; tt < ATCH; ++tt) acc[tt] = 0.f;

    for (int o = 0; o < N_OCC; ++o) {
        float xr[ATCH + 8];
#pragma unroll
        for (int j = 0; j < ATCH + 8; ++j) xr[j] = xo[o][j];
#pragma unroll
        for (int k = 0; k < KSZ; ++k) {
            float w = wqT[(((size_t)l * N_OCC + o) * KSZ + k) * DM + D];
#pragma unroll
            for (int tt = 0; tt < ATCH; ++tt)
                acc[tt] = fmaf(xr[tt + k], w, acc[tt]);
        }
    }
    const int tile = t0 >> 5, tl = t0 & 31;
    const int ch = D >> 5, w = D & 31;
    const int g  = 2 * (w >> 3) + ((w >> 2) & 1);
    const int i2 = w & 3;
    float* qb = qtP + ((((size_t)(b * 16 + tile) * 4 + ch) * 8 + g) * 32 + tl) * 4 + i2;
#pragma unroll
    for (int tt = 0; tt < ATCH; ++tt) qb[tt * 4] = selu2(acc[tt]);
}

// ---------------------------------------------------------------------------
// MFMA fused layer (R9 structure — best measured, 40.3 us, VGPR 104).
// Block = (c, b), 256 threads = 4 waves, 4 t-tiles of 32 per wave. Rolling Q
// prefetch across two named-register sets; wproj staged in LDS.
// NOTE: no min-waves launch bound (R6: (256,4) => catastrophic spill).
// ---------------------------------------------------------------------------
__global__ __launch_bounds__(256) void fused_layer(
    const float* __restrict__ xin, const float* __restrict__ qtP,
    const f16x8* __restrict__ wkh, const f16x8* __restrict__ wvh,
    const float* __restrict__ wproj, float* __restrict__ xout, int l)
{
    const int c = blockIdx.x, b = blockIdx.y;
    const int tid  = threadIdx.x;
    const int wave = tid >> 6;
    const int lane = tid & 63;
    const int tcol = lane & 31;
    const int hi   = lane >> 5;

    // A fragments first: one 16B coalesced load per (tensor, ch)
    const f16x8* wkf = wkh + ((size_t)(l * C_CH + c) * 4) * 64 + lane;
    const f16x8* wvf = wvh + ((size_t)(l * C_CH + c) * 4) * 64 + lane;
    f16x8 ak[4], av[4];
#pragma unroll
    for (int ch = 0; ch < 4; ++ch) {
        ak[ch] = wkf[ch * 64];
        av[ch] = wvf[ch * 64];
    }

    // stage x window [-4, 524) as float row + f16 pair table + wproj row
    __shared__ float xs[528];
    __shared__ unsigned int xs2[527];
    __shared__ float wpj[DM];
    const float* xp = xin + ((size_t)(b * C_CH + c)) * T_LEN;
    for (int i = tid; i < 528; i += 256) {
        int tg = i - 4;
        float a0 = (tg >= 0 && tg < T_LEN) ? xp[tg] : 0.f;
        float a1 = (tg + 1 >= 0 && tg + 1 < T_LEN) ? xp[tg + 1] : 0.f;
        xs[i] = a0;
        if (i < 527) {
            pair_u p;
            p.h[0] = (_Float16)a0;
            p.h[1] = (_Float16)a1;
            xs2[i] = p.u;
        }
    }
    if (tid < DM) wpj[tid] = wproj[((size_t)l * C_CH + c) * DM + tid];
    __syncthreads();

#define LOADQ(p0, p1, p2, p3, chv, tilev) do {                                \
    const float4* qp_ = reinterpret_cast<const float4*>(qtP)                  \
        + (((size_t)(b * 16 + (tilev)) * 4 + (chv)) * 8) * 32 + tcol;         \
    p0 = qp_[(0 + hi) * 32];                                                  \
    p1 = qp_[(2 + hi) * 32];                                                  \
    p2 = qp_[(4 + hi) * 32];                                                  \
    p3 = qp_[(6 + hi) * 32];                                                  \
} while (0)

#define KPROC(chv, p0, p1, p2, p3) do {                                       \
    f32x16 acc_ = zero16();                                                   \
    acc_ = __builtin_amdgcn_mfma_f32_32x32x16_f16(ak[chv], bfr, acc_, 0, 0, 0);\
    float pA = 0.f, pB = 0.f;                                                 \
    pA = fmaf(p0.x, selu2(acc_[0]),  pA);                                     \
    pA = fmaf(p0.y, selu2(acc_[1]),  pA);                                     \
    pA = fmaf(p0.z, selu2(acc_[2]),  pA);                                     \
    pA = fmaf(p0.w, selu2(acc_[3]),  pA);                                     \
    pA = fmaf(p1.x, selu2(acc_[4]),  pA);                                     \
    pA = fmaf(p1.y, selu2(acc_[5]),  pA);                                     \
    pA = fmaf(p1.z, selu2(acc_[6]),  pA);                                     \
    pA = fmaf(p1.w, selu2(acc_[7]),  pA);                                     \
    pB = fmaf(p2.x, selu2(acc_[8]),  pB);                                     \
    pB = fmaf(p2.y, selu2(acc_[9]),  pB);                                     \
    pB = fmaf(p2.z, selu2(acc_[10]), pB);                                     \
    pB = fmaf(p2.w, selu2(acc_[11]), pB);                                     \
    pB = fmaf(p3.x, selu2(acc_[12]), pB);                                     \
    pB = fmaf(p3.y, selu2(acc_[13]), pB);                                     \
    pB = fmaf(p3.z, selu2(acc_[14]), pB);                                     \
    pB = fmaf(p3.w, selu2(acc_[15]), pB);                                     \
    qk[(chv) * 2 + 0] += pA;                                                  \
    qk[(chv) * 2 + 1] += pB;                                                  \
} while (0)

    float4 qa0, qa1, qa2, qa3, qb0, qb1, qb2, qb3;
    LOADQ(qa0, qa1, qa2, qa3, 0, wave * 4);     // tile 0: ch0
    LOADQ(qb0, qb1, qb2, qb3, 1, wave * 4);     // tile 0: ch1

#pragma unroll 1
    for (int ti = 0; ti < 4; ++ti) {
        const int tile = wave * 4 + ti;              // global 32-t tile index
        const int loc0 = tile * 32;                  // t base of this tile
        const int t    = loc0 + tcol;                // this lane's t (may be >=500)

        // B fragment: 4x packed-pair LDS reads, k-slot phi = 8*hi + j
        f16x8 bfr;
        {
            const int base = loc0 + tcol + 8 * hi;
#pragma unroll
            for (int j = 0; j < 4; ++j) {
                pair_u p; p.u = xs2[base + 2 * j];
                bfr[2 * j]     = p.h[0];
                bfr[2 * j + 1] = p.h[1];
            }
        }

        float qk[8];
#pragma unroll
        for (int h = 0; h < 8; ++h) qk[h] = 0.f;

        // pass 1: K conv (MFMA) + selu + per-head Q.K partials,
        // with rolling ch-level prefetch into the other reg set
        KPROC(0, qa0, qa1, qa2, qa3);
        LOADQ(qa0, qa1, qa2, qa3, 2, tile);
        KPROC(1, qb0, qb1, qb2, qb3);
        LOADQ(qb0, qb1, qb2, qb3, 3, tile);
        KPROC(2, qa0, qa1, qa2, qa3);
        KPROC(3, qb0, qb1, qb2, qb3);

        // gates (combine hi-half partials; fold 0.25 * log2e into the scale)
        float g[8];
#pragma unroll
        for (int h = 0; h < 8; ++h) {
            float full = qk[h] + __shfl_xor(qk[h], 32);
            g[h] = selu2(full * (0.25f * LOG2E));
        }

        // prefetch next tile's ch0/ch1 over the V-pass
        const int ntile = (ti < 3) ? tile + 1 : tile;
        LOADQ(qa0, qa1, qa2, qa3, 0, ntile);
        LOADQ(qb0, qb1, qb2, qb3, 1, ntile);

        // pass 2: V conv (MFMA) + selu + wproj-weighted per-head sums
        float outp = 0.f;
#pragma unroll
        for (int ch = 0; ch < 4; ++ch) {
            f32x16 acc = zero16();
            acc = __builtin_amdgcn_mfma_f32_32x32x16_f16(av[ch], bfr, acc, 0, 0, 0);
            float sA = 0.f, sB = 0.f;
#pragma unroll
            for (int I = 0; I < 4; ++I) {
                float4 wq4 = *reinterpret_cast<const float4*>(
                    &wpj[(ch * 8 + 2 * I + hi) * 4]);
#pragma unroll
                for (int i2 = 0; i2 < 4; ++i2) {
                    float vv = selu2(acc[4 * I + i2]);
                    if (I < 2) sA = fmaf((&wq4.x)[i2], vv, sA);
                    else       sB = fmaf((&wq4.x)[i2], vv, sB);
                }
            }
            outp = fmaf(g[ch * 2 + 0], sA, outp);
            outp = fmaf(g[ch * 2 + 1], sB, outp);
        }
        float outf = outp + __shfl_xor(outp, 32);

        if (hi == 0 && t < T_LEN) {
            const float rs = 0.70710678118654752f;
            xout[((size_t)(b * C_CH + c)) * T_LEN + t]
                = (xs[loc0 + tcol + 4] + selu2(outf * LOG2E)) * rs;
        }
    }
#undef LOADQ
#undef KPROC
}

// ---------------------------------------------------------------------------
// Head: 4 outputs per block, 16 chunks; LAST block (atomic counter) does the
// final cross-chunk reduction + bias — no separate head_final launch.
// Counter is zeroed by prep_kernel each call (graph-replay deterministic)
// and re-zeroed by the winner.
// ---------------------------------------------------------------------------
#define NCHUNK 16
#define CHUNK  (C_CH * T_LEN / NCHUNK)      // 4000
#define NOG    4
#define NHBLK  ((N_OUT / NOG) * NCHUNK)     // 160 blocks
__global__ __launch_bounds__(256) void head_kernel(
    const float* __restrict__ x, const float* __restrict__ wh,
    const float* __restrict__ bh, float* __restrict__ part,
    unsigned int* __restrict__ cnt, float* __restrict__ out)
{
    const int o0 = blockIdx.x * NOG;
    const int ch = blockIdx.y;
    const int base = ch * CHUNK;

    float acc[NOG][8];
#pragma unroll
    for (int og = 0; og < NOG; ++og)
#pragma unroll
        for (int b = 0; b < 8; ++b) acc[og][b] = 0.f;

    for (int i = threadIdx.x; i < CHUNK / 4; i += 256) {
        float4 x4[8];
#pragma unroll
        for (int b = 0; b < 8; ++b)
            x4[b] = reinterpret_cast<const float4*>(
                x + (size_t)b * (C_CH * T_LEN) + base)[i];
#pragma unroll
        for (int og = 0; og < NOG; ++og) {
            float4 w4 = reinterpret_cast<const float4*>(
                wh + (size_t)(o0 + og) * (C_CH * T_LEN) + base)[i];
#pragma unroll
            for (int b = 0; b < 8; ++b) {
                acc[og][b] = fmaf(x4[b].x, w4.x, acc[og][b]);
                acc[og][b] = fmaf(x4[b].y, w4.y, acc[og][b]);
                acc[og][b] = fmaf(x4[b].z, w4.z, acc[og][b]);
                acc[og][b] = fmaf(x4[b].w, w4.w, acc[og][b]);
            }
        }
    }

#pragma unroll
    for (int og = 0; og < NOG; ++og)
#pragma unroll
        for (int b = 0; b < 8; ++b)
#pragma unroll
            for (int off = 32; off > 0; off >>= 1)
                acc[og][b] += __shfl_down(acc[og][b], off);

    __shared__ float red[4][NOG][8];
    const int lane = threadIdx.x & 63, wid = threadIdx.x >> 6;
    if (lane == 0)
#pragma unroll
        for (int og = 0; og < NOG; ++og)
#pragma unroll
            for (int b = 0; b < 8; ++b) red[wid][og][b] = acc[og][b];
    __syncthreads();
    if (threadIdx.x < NOG * 8) {
        int og = threadIdx.x >> 3, b = threadIdx.x & 7;
        part[((size_t)(o0 + og) * NCHUNK + ch) * 8 + b]
            = red[0][og][b] + red[1][og][b] + red[2][og][b] + red[3][og][b];
    }

    // last-block final reduction
    __shared__ unsigned int is_last;
    __syncthreads();
    if (threadIdx.x == 0) {
        __threadfence();
        is_last = (atomicAdd(cnt, 1u) == NHBLK - 1) ? 1u : 0u;
    }
    __syncthreads();
    if (is_last) {
        __threadfence();
        for (int i = threadIdx.x; i < N_OUT * 8; i += 256) {
            int o = i >> 3, b = i & 7;
            float s = bh[o];
#pragma unroll
            for (int c2 = 0; c2 < NCHUNK; ++c2)
                s += part[((size_t)o * NCHUNK + c2) * 8 + b];
            out[b * N_OUT + o] = s;
        }
        if (threadIdx.x == 0) *cnt = 0;
    }
}

// ---------------------------------------------------------------------------
extern "C" void kernel_launch(void* const* d_in, const int* in_sizes, int n_in,
                              void* d_out, int out_size, void* d_ws, size_t ws_size,
                              hipStream_t stream) {
    const float* x     = (const float*)d_in[0];
    const int*   occ   = (const int*)  d_in[1];
    const float* wq    = (const float*)d_in[2];
    const float* wk    = (const float*)d_in[3];
    const float* wv    = (const float*)d_in[4];
    const float* wproj = (const float*)d_in[5];
    const float* wh    = (const float*)d_in[6];
    const float* bh    = (const float*)d_in[7];
    float* out = (float*)d_out;

    float* ws  = (float*)d_ws;
    float* wqT = ws;                                   // 48384 f32
    float* qtb = wqT + 2 * N_OCC * KSZ * DM;           // 524288 f32 (Qpack)
    float* xb0 = qtb + (size_t)8 * 16 * DM * 32;       // 512000 f32
    float* xb1 = xb0 + (size_t)8 * C_CH * T_LEN;       // 512000 f32
    float* hp  = xb1 + (size_t)8 * C_CH * T_LEN;       // 5120 f32 (head partials)
    unsigned int* hcnt = (unsigned int*)(hp + N_OUT * NCHUNK * 8);  // 8 f32 slot
    _Float16* wkh = (_Float16*)(hp + N_OUT * NCHUNK * 8 + 8);       // 524288 f16
    _Float16* wvh = wkh + (size_t)2 * C_CH * 4 * 64 * 8;            // 524288 f16

    prep_kernel<<<dim3(256), 256, 0, stream>>>(wq, wk, wv, wqT, wkh, wvh, hcnt);

    // layer 0 (reads the input x directly)
    qconv_kernel<<<dim3(125, 8), 128, 0, stream>>>(x, occ, wqT, qtb, 0);
    fused_layer <<<dim3(128, 8), 256, 0, stream>>>(
        x, qtb, (const f16x8*)wkh, (const f16x8*)wvh, wproj, xb0, 0);

    // layer 1
    qconv_kernel<<<dim3(125, 8), 128, 0, stream>>>(xb0, occ, wqT, qtb, 1);
    fused_layer <<<dim3(128, 8), 256, 0, stream>>>(
        xb0, qtb, (const f16x8*)wkh, (const f16x8*)wvh, wproj, xb1, 1);

    head_kernel<<<dim3(N_OUT / NOG, NCHUNK), 256, 0, stream>>>(
        xb1, wh, bh, hp, hcnt, out);
}

// Round 14
// 110.486 us; speedup vs baseline: 1.0225x; 1.0225x over previous
//
#include <hip/hip_runtime.h>
#include <math.h>

// Problem constants
#define T_LEN   500
#define C_CH    128
#define DM      128     // D_MODEL
#define N_OCC   21
#define KSZ     9
#define N_OUT   40
#define LOG2E   1.44269504088896340736f

typedef _Float16 f16x8 __attribute__((ext_vector_type(8)));
typedef _Float16 f16x2 __attribute__((ext_vector_type(2)));
typedef float    f32x16 __attribute__((ext_vector_type(16)));

union pair_u { unsigned int u; f16x2 h; };

__device__ __forceinline__ float exp2_fast(float y) {
#if __has_builtin(__builtin_amdgcn_exp2f)
    return __builtin_amdgcn_exp2f(y);
#else
    return exp2f(y);
#endif
}

// y = x * log2(e)  ->  returns selu(x).
__device__ __forceinline__ float selu2(float y) {
    const float c1 = 0.7282904300f;          // lambda * ln2
    const float la = 1.7580993408473766f;    // lambda * alpha
    float e = exp2_fast(y);
    return y > 0.f ? c1 * y : fmaf(la, e, -la);
}

__device__ __forceinline__ f32x16 zero16() {
    f32x16 z;
#pragma unroll
    for (int j = 0; j < 16; ++j) z[j] = 0.f;
    return z;
}

// ---------------------------------------------------------------------------
// Combined prep:
//  (1) wqT[(l*21+o)*9+k][D] = wq[l,D,o,k] * log2e
//  (2) wkh/wvh in MFMA A-fragment layout, f16, * log2e
// ---------------------------------------------------------------------------
__global__ void prep_kernel(const float* __restrict__ wq,
                            const float* __restrict__ wk, const float* __restrict__ wv,
                            float* __restrict__ wqT,
                            _Float16* __restrict__ wkh, _Float16* __restrict__ wvh)
{
    int idx = blockIdx.x * 256 + threadIdx.x;          // 65536 threads
    if (idx < 2 * N_OCC * KSZ * DM) {
        int D  = idx & 127;
        int r  = idx >> 7;
        int k  = r % KSZ;
        int r2 = r / KSZ;
        int o  = r2 % N_OCC;
        int l  = r2 / N_OCC;
        wqT[idx] = wq[(((size_t)l * DM + D) * N_OCC + o) * KSZ + k] * LOG2E;
    }
    if (idx < 2 * C_CH * 4 * 64) {
        int lane = idx & 63;
        int ch   = (idx >> 6) & 3;
        int c    = (idx >> 8) & 127;
        int l    = idx >> 15;
        int tcol = lane & 31, hi = lane >> 5;
        int D    = ch * 32 + tcol;
        const float* wkp = wk + ((size_t)l * C_CH * DM + (size_t)c * DM + D) * KSZ;
        const float* wvp = wv + ((size_t)l * C_CH * DM + (size_t)c * DM + D) * KSZ;
#pragma unroll
        for (int j = 0; j < 8; ++j) {
            int k = 8 * hi + j;
            wkh[(size_t)idx * 8 + j] = (k < KSZ) ? (_Float16)(wkp[k] * LOG2E) : (_Float16)0.f;
            wvh[(size_t)idx * 8 + j] = (k < KSZ) ? (_Float16)(wvp[k] * LOG2E) : (_Float16)0.f;
        }
    }
}

// ---------------------------------------------------------------------------
// Q conv, writing Qpack[b][tile][ch][g][t32][i2] (float4-friendly):
//   D = ch*32 + 8I + 4hi + i2, g = 2I+hi
// grid (125, 8), block 128 (one thread per D), 4 t per block
// ---------------------------------------------------------------------------
#define ATCH 4
__global__ __launch_bounds__(128) void qconv_kernel(
    const float* __restrict__ xin, const int* __restrict__ occ,
    const float* __restrict__ wqT, float* __restrict__ qtP, int l)
{
    const int b  = blockIdx.y;
    const int t0 = blockIdx.x * ATCH;
    const int D  = threadIdx.x;
    __shared__ float xo[N_OCC][ATCH + 8];
    for (int i = threadIdx.x; i < N_OCC * (ATCH + 8); i += 128) {
        int o = i / (ATCH + 8), j = i % (ATCH + 8);
        int tg = t0 + j - 4;
        xo[o][j] = (tg >= 0 && tg < T_LEN)
                     ? xin[((size_t)b * C_CH + occ[o]) * T_LEN + tg] : 0.f;
    }
    __syncthreads();

    float acc[ATCH];
#pragma unroll
    for (int tt = 0; tt < ATCH; ++tt) acc[tt] = 0.f;

    for (int o = 0; o < N_OCC; ++o) {
        float xr[ATCH + 8];
#pragma unroll
        for (int j = 0; j < ATCH + 8; ++j) xr[j] = xo[o][j];
#pragma unroll
        for (int k = 0; k < KSZ; ++k) {
            float w = wqT[(((size_t)l * N_OCC + o) * KSZ + k) * DM + D];
#pragma unroll
            for (int tt = 0; tt < ATCH; ++tt)
                acc[tt] = fmaf(xr[tt + k], w, acc[tt]);
        }
    }
    const int tile = t0 >> 5, tl = t0 & 31;
    const int ch = D >> 5, w = D & 31;
    const int g  = 2 * (w >> 3) + ((w >> 2) & 1);
    const int i2 = w & 3;
    float* qb = qtP + ((((size_t)(b * 16 + tile) * 4 + ch) * 8 + g) * 32 + tl) * 4 + i2;
#pragma unroll
    for (int tt = 0; tt < ATCH; ++tt) qb[tt * 4] = selu2(acc[tt]);
}

// ---------------------------------------------------------------------------
// MFMA fused layer (R9/R12 structure, with ak/av moved to LDS to cut VGPRs).
// Block = (c, b), 256 threads = 4 waves, 4 t-tiles of 32 per wave. All 4
// waves share identical per-lane A-fragments (same c), so they're staged in
// LDS once (8 KB) and read per-KPROC via ds_read_b128 — frees ~32 VGPRs to
// raise waves/SIMD from 4 to ~6.
// NOTE: no min-waves launch bound (R6: (256,4) => catastrophic spill).
// ---------------------------------------------------------------------------
__global__ __launch_bounds__(256) void fused_layer(
    const float* __restrict__ xin, const float* __restrict__ qtP,
    const f16x8* __restrict__ wkh, const f16x8* __restrict__ wvh,
    const float* __restrict__ wproj, float* __restrict__ xout, int l)
{
    const int c = blockIdx.x, b = blockIdx.y;
    const int tid  = threadIdx.x;
    const int wave = tid >> 6;
    const int lane = tid & 63;
    const int tcol = lane & 31;
    const int hi   = lane >> 5;

    // stage A fragments in LDS (shared by all 4 waves): coalesced 16B/thread
    __shared__ f16x8 sak[256];
    __shared__ f16x8 sav[256];
    sak[tid] = wkh[((size_t)(l * C_CH + c)) * 256 + tid];
    sav[tid] = wvh[((size_t)(l * C_CH + c)) * 256 + tid];

    // stage x window [-4, 524) as float row + f16 pair table + wproj row
    __shared__ float xs[528];
    __shared__ unsigned int xs2[527];
    __shared__ float wpj[DM];
    const float* xp = xin + ((size_t)(b * C_CH + c)) * T_LEN;
    for (int i = tid; i < 528; i += 256) {
        int tg = i - 4;
        float a0 = (tg >= 0 && tg < T_LEN) ? xp[tg] : 0.f;
        float a1 = (tg + 1 >= 0 && tg + 1 < T_LEN) ? xp[tg + 1] : 0.f;
        xs[i] = a0;
        if (i < 527) {
            pair_u p;
            p.h[0] = (_Float16)a0;
            p.h[1] = (_Float16)a1;
            xs2[i] = p.u;
        }
    }
    if (tid < DM) wpj[tid] = wproj[((size_t)l * C_CH + c) * DM + tid];
    __syncthreads();

#define LOADQ(p0, p1, p2, p3, chv, tilev) do {                                \
    const float4* qp_ = reinterpret_cast<const float4*>(qtP)                  \
        + (((size_t)(b * 16 + (tilev)) * 4 + (chv)) * 8) * 32 + tcol;         \
    p0 = qp_[(0 + hi) * 32];                                                  \
    p1 = qp_[(2 + hi) * 32];                                                  \
    p2 = qp_[(4 + hi) * 32];                                                  \
    p3 = qp_[(6 + hi) * 32];                                                  \
} while (0)

#define KPROC(chv, p0, p1, p2, p3) do {                                       \
    f16x8 ak_ = sak[(chv) * 64 + lane];                                       \
    f32x16 acc_ = zero16();                                                   \
    acc_ = __builtin_amdgcn_mfma_f32_32x32x16_f16(ak_, bfr, acc_, 0, 0, 0);   \
    float pA = 0.f, pB = 0.f;                                                 \
    pA = fmaf(p0.x, selu2(acc_[0]),  pA);                                     \
    pA = fmaf(p0.y, selu2(acc_[1]),  pA);                                     \
    pA = fmaf(p0.z, selu2(acc_[2]),  pA);                                     \
    pA = fmaf(p0.w, selu2(acc_[3]),  pA);                                     \
    pA = fmaf(p1.x, selu2(acc_[4]),  pA);                                     \
    pA = fmaf(p1.y, selu2(acc_[5]),  pA);                                     \
    pA = fmaf(p1.z, selu2(acc_[6]),  pA);                                     \
    pA = fmaf(p1.w, selu2(acc_[7]),  pA);                                     \
    pB = fmaf(p2.x, selu2(acc_[8]),  pB);                                     \
    pB = fmaf(p2.y, selu2(acc_[9]),  pB);                                     \
    pB = fmaf(p2.z, selu2(acc_[10]), pB);                                     \
    pB = fmaf(p2.w, selu2(acc_[11]), pB);                                     \
    pB = fmaf(p3.x, selu2(acc_[12]), pB);                                     \
    pB = fmaf(p3.y, selu2(acc_[13]), pB);                                     \
    pB = fmaf(p3.z, selu2(acc_[14]), pB);                                     \
    pB = fmaf(p3.w, selu2(acc_[15]), pB);                                     \
    qk[(chv) * 2 + 0] += pA;                                                  \
    qk[(chv) * 2 + 1] += pB;                                                  \
} while (0)

    float4 qa0, qa1, qa2, qa3, qb0, qb1, qb2, qb3;
    LOADQ(qa0, qa1, qa2, qa3, 0, wave * 4);     // tile 0: ch0
    LOADQ(qb0, qb1, qb2, qb3, 1, wave * 4);     // tile 0: ch1

#pragma unroll 1
    for (int ti = 0; ti < 4; ++ti) {
        const int tile = wave * 4 + ti;              // global 32-t tile index
        const int loc0 = tile * 32;                  // t base of this tile
        const int t    = loc0 + tcol;                // this lane's t (may be >=500)

        // B fragment: 4x packed-pair LDS reads, k-slot phi = 8*hi + j
        f16x8 bfr;
        {
            const int base = loc0 + tcol + 8 * hi;
#pragma unroll
            for (int j = 0; j < 4; ++j) {
                pair_u p; p.u = xs2[base + 2 * j];
                bfr[2 * j]     = p.h[0];
                bfr[2 * j + 1] = p.h[1];
            }
        }

        float qk[8];
#pragma unroll
        for (int h = 0; h < 8; ++h) qk[h] = 0.f;

        // pass 1: K conv (MFMA) + selu + per-head Q.K partials,
        // with rolling ch-level prefetch into the other reg set
        KPROC(0, qa0, qa1, qa2, qa3);
        LOADQ(qa0, qa1, qa2, qa3, 2, tile);
        KPROC(1, qb0, qb1, qb2, qb3);
        LOADQ(qb0, qb1, qb2, qb3, 3, tile);
        KPROC(2, qa0, qa1, qa2, qa3);
        KPROC(3, qb0, qb1, qb2, qb3);

        // gates (combine hi-half partials; fold 0.25 * log2e into the scale)
        float g[8];
#pragma unroll
        for (int h = 0; h < 8; ++h) {
            float full = qk[h] + __shfl_xor(qk[h], 32);
            g[h] = selu2(full * (0.25f * LOG2E));
        }

        // prefetch next tile's ch0/ch1 over the V-pass
        const int ntile = (ti < 3) ? tile + 1 : tile;
        LOADQ(qa0, qa1, qa2, qa3, 0, ntile);
        LOADQ(qb0, qb1, qb2, qb3, 1, ntile);

        // pass 2: V conv (MFMA) + selu + wproj-weighted per-head sums
        float outp = 0.f;
#pragma unroll
        for (int ch = 0; ch < 4; ++ch) {
            f16x8 av_ = sav[ch * 64 + lane];
            f32x16 acc = zero16();
            acc = __builtin_amdgcn_mfma_f32_32x32x16_f16(av_, bfr, acc, 0, 0, 0);
            float sA = 0.f, sB = 0.f;
#pragma unroll
            for (int I = 0; I < 4; ++I) {
                float4 wq4 = *reinterpret_cast<const float4*>(
                    &wpj[(ch * 8 + 2 * I + hi) * 4]);
#pragma unroll
                for (int i2 = 0; i2 < 4; ++i2) {
                    float vv = selu2(acc[4 * I + i2]);
                    if (I < 2) sA = fmaf((&wq4.x)[i2], vv, sA);
                    else       sB = fmaf((&wq4.x)[i2], vv, sB);
                }
            }
            outp = fmaf(g[ch * 2 + 0], sA, outp);
            outp = fmaf(g[ch * 2 + 1], sB, outp);
        }
        float outf = outp + __shfl_xor(outp, 32);

        if (hi == 0 && t < T_LEN) {
            const float rs = 0.70710678118654752f;
            xout[((size_t)(b * C_CH + c)) * T_LEN + t]
                = (xs[loc0 + tcol + 4] + selu2(outf * LOG2E)) * rs;
        }
    }
#undef LOADQ
#undef KPROC
}

// ---------------------------------------------------------------------------
// Head stage 1: 4 outputs per block so the x-chunk is loaded once and reused.
// grid (10 o-groups, 16 chunks), block 256.
// ---------------------------------------------------------------------------
#define NCHUNK 16
#define CHUNK  (C_CH * T_LEN / NCHUNK)      // 4000
#define NOG    4
__global__ __launch_bounds__(256) void head_partial(
    const float* __restrict__ x, const float* __restrict__ wh,
    float* __restrict__ part)
{
    const int o0 = blockIdx.x * NOG;
    const int ch = blockIdx.y;
    const int base = ch * CHUNK;

    float acc[NOG][8];
#pragma unroll
    for (int og = 0; og < NOG; ++og)
#pragma unroll
        for (int b = 0; b < 8; ++b) acc[og][b] = 0.f;

    for (int i = threadIdx.x; i < CHUNK / 4; i += 256) {
        float4 x4[8];
#pragma unroll
        for (int b = 0; b < 8; ++b)
            x4[b] = reinterpret_cast<const float4*>(
                x + (size_t)b * (C_CH * T_LEN) + base)[i];
#pragma unroll
        for (int og = 0; og < NOG; ++og) {
            float4 w4 = reinterpret_cast<const float4*>(
                wh + (size_t)(o0 + og) * (C_CH * T_LEN) + base)[i];
#pragma unroll
            for (int b = 0; b < 8; ++b) {
                acc[og][b] = fmaf(x4[b].x, w4.x, acc[og][b]);
                acc[og][b] = fmaf(x4[b].y, w4.y, acc[og][b]);
                acc[og][b] = fmaf(x4[b].z, w4.z, acc[og][b]);
                acc[og][b] = fmaf(x4[b].w, w4.w, acc[og][b]);
            }
        }
    }

#pragma unroll
    for (int og = 0; og < NOG; ++og)
#pragma unroll
        for (int b = 0; b < 8; ++b)
#pragma unroll
            for (int off = 32; off > 0; off >>= 1)
                acc[og][b] += __shfl_down(acc[og][b], off);

    __shared__ float red[4][NOG][8];
    const int lane = threadIdx.x & 63, wid = threadIdx.x >> 6;
    if (lane == 0)
#pragma unroll
        for (int og = 0; og < NOG; ++og)
#pragma unroll
            for (int b = 0; b < 8; ++b) red[wid][og][b] = acc[og][b];
    __syncthreads();
    if (threadIdx.x < NOG * 8) {
        int og = threadIdx.x >> 3, b = threadIdx.x & 7;
        part[((size_t)(o0 + og) * NCHUNK + ch) * 8 + b]
            = red[0][og][b] + red[1][og][b] + red[2][og][b] + red[3][og][b];
    }
}

// Head stage 2: out[b,o] = b_head[o] + sum_ch part[o][ch][b].  1 block, 320 thr
__global__ __launch_bounds__(320) void head_final(
    const float* __restrict__ part, const float* __restrict__ bh,
    float* __restrict__ out)
{
    int i = threadIdx.x;
    if (i >= N_OUT * 8) return;
    int o = i >> 3, b = i & 7;
    float s = bh[o];
#pragma unroll
    for (int ch = 0; ch < NCHUNK; ++ch)
        s += part[((size_t)o * NCHUNK + ch) * 8 + b];
    out[b * N_OUT + o] = s;
}

// ---------------------------------------------------------------------------
extern "C" void kernel_launch(void* const* d_in, const int* in_sizes, int n_in,
                              void* d_out, int out_size, void* d_ws, size_t ws_size,
                              hipStream_t stream) {
    const float* x     = (const float*)d_in[0];
    const int*   occ   = (const int*)  d_in[1];
    const float* wq    = (const float*)d_in[2];
    const float* wk    = (const float*)d_in[3];
    const float* wv    = (const float*)d_in[4];
    const float* wproj = (const float*)d_in[5];
    const float* wh    = (const float*)d_in[6];
    const float* bh    = (const float*)d_in[7];
    float* out = (float*)d_out;

    float* ws  = (float*)d_ws;
    float* wqT = ws;                                   // 48384 f32
    float* qtb = wqT + 2 * N_OCC * KSZ * DM;           // 524288 f32 (Qpack)
    float* xb0 = qtb + (size_t)8 * 16 * DM * 32;       // 512000 f32
    float* xb1 = xb0 + (size_t)8 * C_CH * T_LEN;       // 512000 f32
    float* hp  = xb1 + (size_t)8 * C_CH * T_LEN;       // 40*16*8 = 5120 f32
    _Float16* wkh = (_Float16*)(hp + N_OUT * NCHUNK * 8);  // 524288 f16
    _Float16* wvh = wkh + (size_t)2 * C_CH * 4 * 64 * 8;   // 524288 f16

    prep_kernel<<<dim3(256), 256, 0, stream>>>(wq, wk, wv, wqT, wkh, wvh);

    // layer 0 (reads the input x directly)
    qconv_kernel<<<dim3(125, 8), 128, 0, stream>>>(x, occ, wqT, qtb, 0);
    fused_layer <<<dim3(128, 8), 256, 0, stream>>>(
        x, qtb, (const f16x8*)wkh, (const f16x8*)wvh, wproj, xb0, 0);

    // layer 1
    qconv_kernel<<<dim3(125, 8), 128, 0, stream>>>(xb0, occ, wqT, qtb, 1);
    fused_layer <<<dim3(128, 8), 256, 0, stream>>>(
        xb0, qtb, (const f16x8*)wkh, (const f16x8*)wvh, wproj, xb1, 1);

    head_partial<<<dim3(N_OUT / NOG, NCHUNK), 256, 0, stream>>>(xb1, wh, hp);
    head_final  <<<dim3(1), 320, 0, stream>>>(hp, bh, out);
}